// Round 4
// baseline (102.913 us; speedup 1.0000x reference)
//
#include <hip/hip_runtime.h>

typedef float float4v __attribute__((ext_vector_type(4)));

#define DIM 128

// One block (4 waves, 256 threads) per segment. batch is sorted, so each
// segment is a contiguous row range [r0, r1) found by binary search.
// Block-stride streaming max over the range, LDS combine, direct f32 store.
__global__ __launch_bounds__(256, 8) void segmax_block_kernel(
    const float* __restrict__ x, const int* __restrict__ batch,
    float* __restrict__ out, int N)
{
    __shared__ float red[4][DIM];

    int seg = blockIdx.x;
    int tid = threadIdx.x;
    int w = tid >> 6;              // wave id 0..3
    int lane = tid & 63;
    int half = lane >> 5;          // half-wave: which row of a pair
    int c = (lane & 31) * 4;       // column offset (float4 per lane)

    // lower_bound: lane parity picks the query (seg for even lanes, seg+1 for
    // odd). All lanes run the same 20-iteration halving loop — no divergence.
    int g = seg + (lane & 1);
    int lo = 0, hi = N;
    while (lo < hi) {
        int mid = (lo + hi) >> 1;
        if (batch[mid] < g) lo = mid + 1; else hi = mid;
    }
    int r0 = __shfl(lo, 0);
    int r1 = __shfl(lo, 1);

    float4v acc;
    acc.x = -INFINITY; acc.y = -INFINITY; acc.z = -INFINITY; acc.w = -INFINITY;

    const float* xc = x + c;
    // Block covers 8 consecutive rows per round: row = r0 + 2*w + half + k*8.
    int r = r0 + 2 * w + half;

    // Unroll 4 rounds: 4 dwordx4 loads in flight before any use.
    for (; r + 24 < r1; r += 32) {
        float4v v0 = *(const float4v*)(xc + (size_t)r * DIM);
        float4v v1 = *(const float4v*)(xc + (size_t)(r + 8) * DIM);
        float4v v2 = *(const float4v*)(xc + (size_t)(r + 16) * DIM);
        float4v v3 = *(const float4v*)(xc + (size_t)(r + 24) * DIM);
        acc.x = fmaxf(fmaxf(acc.x, v0.x), fmaxf(v1.x, v2.x));
        acc.y = fmaxf(fmaxf(acc.y, v0.y), fmaxf(v1.y, v2.y));
        acc.z = fmaxf(fmaxf(acc.z, v0.z), fmaxf(v1.z, v2.z));
        acc.w = fmaxf(fmaxf(acc.w, v0.w), fmaxf(v1.w, v2.w));
        acc.x = fmaxf(acc.x, v3.x);
        acc.y = fmaxf(acc.y, v3.y);
        acc.z = fmaxf(acc.z, v3.z);
        acc.w = fmaxf(acc.w, v3.w);
    }
    for (; r < r1; r += 8) {
        float4v v = *(const float4v*)(xc + (size_t)r * DIM);
        acc.x = fmaxf(acc.x, v.x);
        acc.y = fmaxf(acc.y, v.y);
        acc.z = fmaxf(acc.z, v.z);
        acc.w = fmaxf(acc.w, v.w);
    }

    // Combine the two half-wave partials within the wave.
    acc.x = fmaxf(acc.x, __shfl_xor(acc.x, 32));
    acc.y = fmaxf(acc.y, __shfl_xor(acc.y, 32));
    acc.z = fmaxf(acc.z, __shfl_xor(acc.z, 32));
    acc.w = fmaxf(acc.w, __shfl_xor(acc.w, 32));

    // Cross-wave combine via LDS.
    if (half == 0) {
        *(float4v*)&red[w][c] = acc;
    }
    __syncthreads();
    if (tid < 32) {
        int cc = tid * 4;
        float4v a = *(const float4v*)&red[0][cc];
        float4v b = *(const float4v*)&red[1][cc];
        float4v d = *(const float4v*)&red[2][cc];
        float4v e = *(const float4v*)&red[3][cc];
        a.x = fmaxf(fmaxf(a.x, b.x), fmaxf(d.x, e.x));
        a.y = fmaxf(fmaxf(a.y, b.y), fmaxf(d.y, e.y));
        a.z = fmaxf(fmaxf(a.z, b.z), fmaxf(d.z, e.z));
        a.w = fmaxf(fmaxf(a.w, b.w), fmaxf(d.w, e.w));
        *(float4v*)(out + (size_t)seg * DIM + cc) = a;
    }
}

extern "C" void kernel_launch(void* const* d_in, const int* in_sizes, int n_in,
                              void* d_out, int out_size, void* d_ws, size_t ws_size,
                              hipStream_t stream) {
    const float* x = (const float*)d_in[0];
    const int* batch = (const int*)d_in[1];
    float* out = (float*)d_out;

    int N = in_sizes[1];              // number of rows
    int G = out_size / DIM;           // number of segments

    segmax_block_kernel<<<G, 256, 0, stream>>>(x, batch, out, N);
}

// Round 5
// 99.253 us; speedup vs baseline: 1.0369x; 1.0369x over previous
//
#include <hip/hip_runtime.h>

typedef float float4v __attribute__((ext_vector_type(4)));

#define DIM 128

// One block (2 waves, 128 threads) per segment. batch is sorted; segment g
// occupies rows [lower_bound(g), lower_bound(g+1)). Bounds found by a
// cooperative 32-ary ballot search (4 dependent gathers, not 20 serial loads).
// Then branch-free block-stride streaming max, LDS combine, direct f32 store.
__global__ __launch_bounds__(128, 8) void segmax_kernel(
    const float* __restrict__ x, const int* __restrict__ batch,
    float* __restrict__ out, int N)
{
    __shared__ float red[2][DIM];

    int seg  = blockIdx.x;
    int tid  = threadIdx.x;
    int w    = tid >> 6;        // wave id 0/1
    int lane = tid & 63;
    int sub  = lane & 31;       // position within 32-lane search group
    int which = lane >> 5;      // 0: query seg, 1: query seg+1 (also half-wave id)
    int c    = sub * 4;         // column offset (float4 per lane)

    // ---- cooperative 32-ary lower_bound over sorted batch ----
    int g = seg + which;
    unsigned long long gmask = which ? 0xFFFFFFFF00000000ULL : 0x00000000FFFFFFFFULL;
    int lo = 0, len = N;
    #pragma unroll
    for (int it = 0; it < 4; ++it) {
        int L = len;
        int p = lo + ((sub * L) >> 5);          // 32 evenly spaced probes
        int pos = min(p, N - 1);
        bool pred = (L > 0) && (batch[pos] < g);
        unsigned long long bal = __ballot(pred);
        int cnt = __popcll(bal & gmask);        // index of first probe >= g
        if (L > 32) {                           // uniform within each 32-group
            int nlo = (cnt == 0)  ? lo       : (lo + (((cnt - 1) * L) >> 5) + 1);
            int pc  = (cnt == 32) ? (lo + L) : (lo + ((cnt * L) >> 5));
            lo = nlo;
            len = pc - nlo;                     // <= ceil(L/32)
        }
    }
    {   // final: len <= 32, one parallel probe resolves exactly
        int pos = min(lo + ((sub < len) ? sub : 0), N - 1);
        bool pred = (sub < len) && (batch[pos] < g);
        unsigned long long bal = __ballot(pred);
        lo += __popcll(bal & gmask);
    }
    int r0 = __shfl(lo, 0);     // lower_bound(seg)
    int r1 = __shfl(lo, 32);    // lower_bound(seg+1)

    // ---- branch-free streaming max over [r0, r1) ----
    float4v acc;
    acc.x = -INFINITY; acc.y = -INFINITY; acc.z = -INFINITY; acc.w = -INFINITY;

    const float* xc = x + c;
    int half = which;
    // Block covers 4 consecutive rows per round: row = r0 + 2*w + half + 4k.
    int r = r0 + 2 * w + half;

    // Unroll 4: 4 dwordx4 loads in flight before any use; block-round spans
    // 16 consecutive rows (fully coalesced).
    for (; r + 12 < r1; r += 16) {
        float4v v0 = *(const float4v*)(xc + (size_t)r * DIM);
        float4v v1 = *(const float4v*)(xc + (size_t)(r + 4) * DIM);
        float4v v2 = *(const float4v*)(xc + (size_t)(r + 8) * DIM);
        float4v v3 = *(const float4v*)(xc + (size_t)(r + 12) * DIM);
        acc.x = fmaxf(fmaxf(acc.x, v0.x), fmaxf(v1.x, v2.x));
        acc.y = fmaxf(fmaxf(acc.y, v0.y), fmaxf(v1.y, v2.y));
        acc.z = fmaxf(fmaxf(acc.z, v0.z), fmaxf(v1.z, v2.z));
        acc.w = fmaxf(fmaxf(acc.w, v0.w), fmaxf(v1.w, v2.w));
        acc.x = fmaxf(acc.x, v3.x);
        acc.y = fmaxf(acc.y, v3.y);
        acc.z = fmaxf(acc.z, v3.z);
        acc.w = fmaxf(acc.w, v3.w);
    }
    for (; r < r1; r += 4) {
        float4v v = *(const float4v*)(xc + (size_t)r * DIM);
        acc.x = fmaxf(acc.x, v.x);
        acc.y = fmaxf(acc.y, v.y);
        acc.z = fmaxf(acc.z, v.z);
        acc.w = fmaxf(acc.w, v.w);
    }

    // Combine the two half-wave partials within the wave.
    acc.x = fmaxf(acc.x, __shfl_xor(acc.x, 32));
    acc.y = fmaxf(acc.y, __shfl_xor(acc.y, 32));
    acc.z = fmaxf(acc.z, __shfl_xor(acc.z, 32));
    acc.w = fmaxf(acc.w, __shfl_xor(acc.w, 32));

    // Cross-wave combine via LDS, then direct store.
    if (half == 0) {
        *(float4v*)&red[w][c] = acc;
    }
    __syncthreads();
    if (tid < 32) {
        int cc = tid * 4;
        float4v a = *(const float4v*)&red[0][cc];
        float4v b = *(const float4v*)&red[1][cc];
        a.x = fmaxf(a.x, b.x);
        a.y = fmaxf(a.y, b.y);
        a.z = fmaxf(a.z, b.z);
        a.w = fmaxf(a.w, b.w);
        *(float4v*)(out + (size_t)seg * DIM + cc) = a;
    }
}

extern "C" void kernel_launch(void* const* d_in, const int* in_sizes, int n_in,
                              void* d_out, int out_size, void* d_ws, size_t ws_size,
                              hipStream_t stream) {
    const float* x = (const float*)d_in[0];
    const int* batch = (const int*)d_in[1];
    float* out = (float*)d_out;

    int N = in_sizes[1];              // number of rows
    int G = out_size / DIM;           // number of segments

    segmax_kernel<<<G, 128, 0, stream>>>(x, batch, out, N);
}

// Round 6
// 86.336 us; speedup vs baseline: 1.1920x; 1.1496x over previous
//
#include <hip/hip_runtime.h>

typedef float float4v __attribute__((ext_vector_type(4)));

#define DIM 128

__device__ __forceinline__ float4v ntload(const float* p) {
    return __builtin_nontemporal_load((const float4v*)p);
}

__device__ __forceinline__ void accmax(float4v& acc, const float4v& v) {
    acc.x = fmaxf(acc.x, v.x);
    acc.y = fmaxf(acc.y, v.y);
    acc.z = fmaxf(acc.z, v.z);
    acc.w = fmaxf(acc.w, v.w);
}

// One block (2 waves, 128 threads) per segment. batch is sorted; segment g
// occupies rows [lower_bound(g), lower_bound(g+1)). Bounds via cooperative
// 32-ary ballot search. Streaming max with an explicit double-buffered load
// pipeline (next 4 loads issued before current 4 are consumed), NT loads.
__global__ __launch_bounds__(128, 4) void segmax_kernel(
    const float* __restrict__ x, const int* __restrict__ batch,
    float* __restrict__ out, int N)
{
    __shared__ float red[2][DIM];

    int seg  = blockIdx.x;
    int tid  = threadIdx.x;
    int w    = tid >> 6;        // wave id 0/1
    int lane = tid & 63;
    int sub  = lane & 31;       // position within 32-lane search group
    int which = lane >> 5;      // 0: query seg, 1: query seg+1 (also half-wave id)
    int c    = sub * 4;         // column offset (float4 per lane)

    // ---- cooperative 32-ary lower_bound over sorted batch ----
    int g = seg + which;
    unsigned long long gmask = which ? 0xFFFFFFFF00000000ULL : 0x00000000FFFFFFFFULL;
    int lo = 0, len = N;
    #pragma unroll
    for (int it = 0; it < 4; ++it) {
        int L = len;
        int p = lo + ((sub * L) >> 5);          // 32 evenly spaced probes
        int pos = min(p, N - 1);
        bool pred = (L > 0) && (batch[pos] < g);
        unsigned long long bal = __ballot(pred);
        int cnt = __popcll(bal & gmask);        // index of first probe >= g
        if (L > 32) {                           // uniform within each 32-group
            int nlo = (cnt == 0)  ? lo       : (lo + (((cnt - 1) * L) >> 5) + 1);
            int pc  = (cnt == 32) ? (lo + L) : (lo + ((cnt * L) >> 5));
            lo = nlo;
            len = pc - nlo;                     // <= ceil(L/32)
        }
    }
    {   // final: len <= 32, one parallel probe resolves exactly
        int pos = min(lo + ((sub < len) ? sub : 0), N - 1);
        bool pred = (sub < len) && (batch[pos] < g);
        unsigned long long bal = __ballot(pred);
        lo += __popcll(bal & gmask);
    }
    int r0 = __shfl(lo, 0);     // lower_bound(seg)
    int r1 = __shfl(lo, 32);    // lower_bound(seg+1)

    // ---- streaming max over [r0, r1), double-buffered load pipeline ----
    float4v acc;
    acc.x = -INFINITY; acc.y = -INFINITY; acc.z = -INFINITY; acc.w = -INFINITY;

    const float* xc = x + c;
    int half = which;
    // Block covers 4 consecutive rows per round: row = r0 + 2*w + half + 4k.
    int r = r0 + 2 * w + half;

    if (r + 12 < r1) {
        // Prologue: fill pipeline with 4 loads (rows r, r+4, r+8, r+12).
        float4v a0 = ntload(xc + (size_t)r * DIM);
        float4v a1 = ntload(xc + (size_t)(r + 4) * DIM);
        float4v a2 = ntload(xc + (size_t)(r + 8) * DIM);
        float4v a3 = ntload(xc + (size_t)(r + 12) * DIM);
        r += 16;
        // Steady state: issue the NEXT 4 loads before consuming the current 4,
        // so 4-8 dwordx4 loads stay in flight per wave at all times.
        for (; r + 12 < r1; r += 16) {
            float4v b0 = ntload(xc + (size_t)r * DIM);
            float4v b1 = ntload(xc + (size_t)(r + 4) * DIM);
            float4v b2 = ntload(xc + (size_t)(r + 8) * DIM);
            float4v b3 = ntload(xc + (size_t)(r + 12) * DIM);
            acc.x = fmaxf(fmaxf(acc.x, a0.x), fmaxf(a1.x, a2.x));
            acc.y = fmaxf(fmaxf(acc.y, a0.y), fmaxf(a1.y, a2.y));
            acc.z = fmaxf(fmaxf(acc.z, a0.z), fmaxf(a1.z, a2.z));
            acc.w = fmaxf(fmaxf(acc.w, a0.w), fmaxf(a1.w, a2.w));
            acc.x = fmaxf(acc.x, a3.x);
            acc.y = fmaxf(acc.y, a3.y);
            acc.z = fmaxf(acc.z, a3.z);
            acc.w = fmaxf(acc.w, a3.w);
            a0 = b0; a1 = b1; a2 = b2; a3 = b3;
        }
        // Drain pipeline.
        acc.x = fmaxf(fmaxf(acc.x, a0.x), fmaxf(a1.x, a2.x));
        acc.y = fmaxf(fmaxf(acc.y, a0.y), fmaxf(a1.y, a2.y));
        acc.z = fmaxf(fmaxf(acc.z, a0.z), fmaxf(a1.z, a2.z));
        acc.w = fmaxf(fmaxf(acc.w, a0.w), fmaxf(a1.w, a2.w));
        acc.x = fmaxf(acc.x, a3.x);
        acc.y = fmaxf(acc.y, a3.y);
        acc.z = fmaxf(acc.z, a3.z);
        acc.w = fmaxf(acc.w, a3.w);
    }
    // Tail rows.
    for (; r < r1; r += 4) {
        float4v v = ntload(xc + (size_t)r * DIM);
        accmax(acc, v);
    }

    // Combine the two half-wave partials within the wave.
    acc.x = fmaxf(acc.x, __shfl_xor(acc.x, 32));
    acc.y = fmaxf(acc.y, __shfl_xor(acc.y, 32));
    acc.z = fmaxf(acc.z, __shfl_xor(acc.z, 32));
    acc.w = fmaxf(acc.w, __shfl_xor(acc.w, 32));

    // Cross-wave combine via LDS, then direct store.
    if (half == 0) {
        *(float4v*)&red[w][c] = acc;
    }
    __syncthreads();
    if (tid < 32) {
        int cc = tid * 4;
        float4v a = *(const float4v*)&red[0][cc];
        float4v b = *(const float4v*)&red[1][cc];
        a.x = fmaxf(a.x, b.x);
        a.y = fmaxf(a.y, b.y);
        a.z = fmaxf(a.z, b.z);
        a.w = fmaxf(a.w, b.w);
        *(float4v*)(out + (size_t)seg * DIM + cc) = a;
    }
}

extern "C" void kernel_launch(void* const* d_in, const int* in_sizes, int n_in,
                              void* d_out, int out_size, void* d_ws, size_t ws_size,
                              hipStream_t stream) {
    const float* x = (const float*)d_in[0];
    const int* batch = (const int*)d_in[1];
    float* out = (float*)d_out;

    int N = in_sizes[1];              // number of rows
    int G = out_size / DIM;           // number of segments

    segmax_kernel<<<G, 128, 0, stream>>>(x, batch, out, N);
}